// Round 1
// baseline (6010.814 us; speedup 1.0000x reference)
//
#include <hip/hip_runtime.h>
#include <math.h>

#define Bn   16
#define CIN  8
#define TT   20
#define HH   64
#define WW   64
#define COUT 32
#define CTOT (CIN + COUT)   // 40
#define HW   (HH * WW)      // 4096
#define NTHREADS 256
#define NPOS 16             // positions per thread: 4096 / 256

__device__ inline float sigm(float x) {
    return 1.0f / (1.0f + __expf(-x));
}
__device__ inline float tanh_fast(float x) {
    x = fminf(fmaxf(x, -15.0f), 15.0f);
    float e = __expf(2.0f * x);
    return (e - 1.0f) / (e + 1.0f);
}

__global__ __launch_bounds__(NTHREADS) void convlstm_step(
    const float* __restrict__ X,     // (B, CIN, T, H, W)
    const float* __restrict__ Wt,    // (4*COUT, CTOT, 3, 3)
    const float* __restrict__ bias,  // (4*COUT)
    const float* __restrict__ Wci,   // (COUT, H, W)
    const float* __restrict__ Wcf,
    const float* __restrict__ Wco,
    float* __restrict__ out,         // (B, COUT, T, H, W) — h history lives here
    float* __restrict__ c_state,     // (B, COUT, H, W) in d_ws
    int t)
{
    __shared__ float ws[4][CTOT * 9];
    __shared__ float bs[4];

    const int b   = blockIdx.x / COUT;
    const int co  = blockIdx.x % COUT;
    const int tid = threadIdx.x;

    // Stage this block's 4 gate-channel weight sets into LDS.
    for (int g = 0; g < 4; ++g) {
        const float* wg = Wt + (size_t)(g * COUT + co) * CTOT * 9;
        for (int i = tid; i < CTOT * 9; i += NTHREADS) ws[g][i] = wg[i];
    }
    if (tid < 4) bs[tid] = bias[tid * COUT + co];
    __syncthreads();

    const int x  = tid & 63;
    const int y0 = tid >> 6;   // 0..3; thread covers rows y0 + 4*i

    float acc0[NPOS], acc1[NPOS], acc2[NPOS], acc3[NPOS];
    const float b0 = bs[0], b1 = bs[1], b2 = bs[2], b3 = bs[3];
#pragma unroll
    for (int i = 0; i < NPOS; ++i) {
        acc0[i] = b0; acc1[i] = b1; acc2[i] = b2; acc3[i] = b3;
    }

    const int cmax = (t == 0) ? CIN : CTOT;  // h==0 at t==0, skip those channels
    for (int ci = 0; ci < cmax; ++ci) {
        const float* src;
        if (ci < CIN)
            src = X + (((size_t)b * CIN + ci) * TT + t) * HW;
        else
            src = out + (((size_t)b * COUT + (ci - CIN)) * TT + (t - 1)) * HW;

#pragma unroll
        for (int ky = 0; ky < 3; ++ky) {
#pragma unroll
            for (int kx = 0; kx < 3; ++kx) {
                const int widx = ci * 9 + ky * 3 + kx;
                const float w0 = ws[0][widx];
                const float w1 = ws[1][widx];
                const float w2 = ws[2][widx];
                const float w3 = ws[3][widx];
                const int xx = x + kx - 1;
                const bool xok = (unsigned)xx < (unsigned)WW;
#pragma unroll
                for (int i = 0; i < NPOS; ++i) {
                    const int yy = y0 + i * 4 + ky - 1;
                    const bool ok = xok && ((unsigned)yy < (unsigned)HH);
                    const float v = ok ? src[yy * WW + xx] : 0.0f;
                    acc0[i] = fmaf(v, w0, acc0[i]);
                    acc1[i] = fmaf(v, w1, acc1[i]);
                    acc2[i] = fmaf(v, w2, acc2[i]);
                    acc3[i] = fmaf(v, w3, acc3[i]);
                }
            }
        }
    }

    // LSTM pointwise epilogue
    const size_t base_state = ((size_t)b * COUT + co) * HW;
    const size_t base_out   = (((size_t)b * COUT + co) * TT + t) * HW;
    const float* pci = Wci + (size_t)co * HW;
    const float* pcf = Wcf + (size_t)co * HW;
    const float* pco = Wco + (size_t)co * HW;

#pragma unroll
    for (int i = 0; i < NPOS; ++i) {
        const int pos = tid + i * NTHREADS;
        const float cprev = (t == 0) ? 0.0f : c_state[base_state + pos];
        const float wci_v = pci[pos];
        const float wcf_v = pcf[pos];
        const float wco_v = pco[pos];

        const float ig = sigm(acc0[i] + wci_v * cprev);
        const float fg = sigm(acc1[i] + wcf_v * cprev);
        const float cn = fg * cprev + ig * tanh_fast(acc2[i]);
        const float og = sigm(acc3[i] + wco_v * cn);
        const float hn = og * tanh_fast(cn);

        c_state[base_state + pos] = cn;
        out[base_out + pos] = hn;
    }
}

extern "C" void kernel_launch(void* const* d_in, const int* in_sizes, int n_in,
                              void* d_out, int out_size, void* d_ws, size_t ws_size,
                              hipStream_t stream) {
    const float* X    = (const float*)d_in[0];
    const float* Wt   = (const float*)d_in[1];
    const float* bias = (const float*)d_in[2];
    const float* Wci  = (const float*)d_in[3];
    const float* Wcf  = (const float*)d_in[4];
    const float* Wco  = (const float*)d_in[5];
    float* out = (float*)d_out;
    float* c_state = (float*)d_ws;   // B*COUT*H*W floats = 8.4 MB

    dim3 grid(Bn * COUT);
    dim3 block(NTHREADS);
    for (int t = 0; t < TT; ++t) {
        convlstm_step<<<grid, block, 0, stream>>>(X, Wt, bias, Wci, Wcf, Wco,
                                                  out, c_state, t);
    }
}

// Round 2
// 699.274 us; speedup vs baseline: 8.5958x; 8.5958x over previous
//
#include <hip/hip_runtime.h>
#include <math.h>

#define Bn   16
#define CIN  8
#define NT   20
#define HH   64
#define WW   64
#define COUT 32
#define HW   4096
#define NTHREADS 256

typedef __attribute__((ext_vector_type(8)))  short bf16x8;
typedef __attribute__((ext_vector_type(16))) float f32x16;
typedef __attribute__((ext_vector_type(4)))  int   int4v;

__device__ inline unsigned short f2bf(float f) {
    unsigned u = __builtin_bit_cast(unsigned, f);
    u += 0x7fffu + ((u >> 16) & 1u);          // round-to-nearest-even
    return (unsigned short)(u >> 16);
}

// Build A-fragment-ready bf16 weights in ws:
// Wbf linear index = (((tap*3 + kb)*2 + half)*128 + m)*8 + e,  ch = kb*16 + half*8 + e (pad ch>=40 with 0)
__global__ __launch_bounds__(256) void prep_w(const float* __restrict__ W,
                                              unsigned short* __restrict__ Wbf) {
    int idx = blockIdx.x * 256 + threadIdx.x;        // 9*3*2*128*8 = 55296 total
    if (idx >= 9 * 3 * 2 * 128 * 8) return;
    int e    = idx & 7;
    int m    = (idx >> 3) & 127;
    int half = (idx >> 10) & 1;
    int fk   = idx >> 11;            // tap*3 + kb
    int kb   = fk % 3;
    int tap  = fk / 3;
    int ch   = kb * 16 + half * 8 + e;
    float v = 0.0f;
    if (ch < 40) v = W[(size_t)(m * 40 + ch) * 9 + tap];
    Wbf[idx] = f2bf(v);
}

__global__ __launch_bounds__(NTHREADS, 2) void convlstm_step(
    const float* __restrict__ X,                 // (B, CIN, T, H, W) fp32
    const unsigned short* __restrict__ Wbf,      // prepped bf16 weights
    const float* __restrict__ bias,              // (128)
    const float* __restrict__ Wci,
    const float* __restrict__ Wcf,
    const float* __restrict__ Wco,
    float* __restrict__ out,                     // (B, COUT, T, H, W); h history lives here
    float* __restrict__ c_state,                 // (B, COUT, H, W) in ws
    int t)
{
    // LDS: input tile (swizzled bf16, 33792 B) unioned with gates f32 [128][128] (65536 B),
    // plus bias cache.
    __shared__ __align__(16) unsigned char smem[66048];
    float* gates = (float*)smem;
    float* lds_b = (float*)(smem + 65536);

    const int tid = threadIdx.x;
    const int b   = blockIdx.x >> 5;    // batch
    const int TI  = blockIdx.x & 31;    // tile: rows 2TI, 2TI+1 (all 64 cols)
    const int r0  = TI * 2;

    // ---- Pass A: zero the input tile region (covers halo + ch-pad) + bias ----
    {
        int4v z = {0, 0, 0, 0};
#pragma unroll
        for (int j = 0; j < 9; ++j) {
            int id = tid + j * 256;
            if (id < 2112) *(int4v*)(smem + id * 16) = z;   // 2112*16 = 33792 B
        }
        if (tid < 128) lds_b[tid] = bias[tid];
    }
    __syncthreads();

    // ---- Pass B: fill interior. tile cell (lr 0..3, lc 0..65) holds 64 ch-slots (40 used).
    // Swizzle: cells paired by col; 16 slots of 16B per 256B pair-cell;
    // slot = ((lc&1)<<3 | (ch>>3)) ^ ((lc>>1)&15); byte = (lr*33 + (lc>>1))*256 + slot*16 + (ch&7)*2
    for (int j = 0; j < 40; ++j) {
        int idx = tid + j * 256;        // 4 rows * 40 ch * 64 cols = 10240
        int col = idx & 63;
        int rc  = idx >> 6;             // 0..159
        int lr  = rc / 40;
        int ch  = rc - lr * 40;
        int gr  = r0 + lr - 1;
        float v = 0.0f;
        if ((unsigned)gr < 64u) {
            if (ch < 8)
                v = X[(((size_t)(b * CIN + ch) * NT + t) << 12) + (gr << 6) + col];
            else if (t > 0)
                v = out[(((size_t)(b * COUT + (ch - 8)) * NT + (t - 1)) << 12) + (gr << 6) + col];
        }
        int lc   = col + 1;
        int slot = (((lc & 1) << 3) + (ch >> 3)) ^ ((lc >> 1) & 15);
        int byte = (lr * 33 + (lc >> 1)) * 256 + slot * 16 + (ch & 7) * 2;
        *(unsigned short*)(smem + byte) = f2bf(v);
    }

    // ---- A-fragments: 27 per wave (9 taps x 3 k-blocks), from L2-resident Wbf ----
    const int wid  = tid >> 6;          // gate type (m-block)
    const int lane = tid & 63;
    const int lm   = lane & 31;
    const int half = lane >> 5;

    bf16x8 Af[27];
#pragma unroll
    for (int f = 0; f < 27; ++f)
        Af[f] = *(const bf16x8*)(Wbf + (size_t)((f * 2 + half) * 128 + wid * 32 + lm) * 8);

    f32x16 acc[4];
#pragma unroll
    for (int nb = 0; nb < 4; ++nb)
#pragma unroll
        for (int r = 0; r < 16; ++r) acc[nb][r] = 0.0f;

    __syncthreads();

    // ---- K loop: 9 taps x 3 k-blocks x 4 n-blocks ----
#pragma unroll
    for (int dy = 0; dy < 3; ++dy)
#pragma unroll
        for (int dx = 0; dx < 3; ++dx)
#pragma unroll
            for (int kb = 0; kb < 3; ++kb) {
                const int f    = (dy * 3 + dx) * 3 + kb;
                const int cidx = kb * 2 + half;
#pragma unroll
                for (int nb = 0; nb < 4; ++nb) {
                    const int lr   = (nb >> 1) + dy;
                    const int lc   = lm + (nb & 1) * 32 + dx;
                    const int slot = (((lc & 1) << 3) + cidx) ^ ((lc >> 1) & 15);
                    const bf16x8 bf =
                        *(const bf16x8*)(smem + (lr * 33 + (lc >> 1)) * 256 + slot * 16);
                    acc[nb] = __builtin_amdgcn_mfma_f32_32x32x16_bf16(Af[f], bf, acc[nb], 0, 0, 0);
                }
            }

    __syncthreads();   // everyone done reading the tile before we overwrite with gates

    // ---- spill gates to LDS: C layout col=lane&31, row=(r&3)+8*(r>>2)+4*half ----
#pragma unroll
    for (int nb = 0; nb < 4; ++nb) {
        const int colp = nb * 32 + lm;
#pragma unroll
        for (int r = 0; r < 16; ++r) {
            const int row = wid * 32 + (r & 3) + 8 * (r >> 2) + 4 * half;
            gates[row * 128 + colp] = acc[nb][r];
        }
    }
    __syncthreads();

    // ---- LSTM pointwise epilogue (fp32, accurate activations) ----
    const int pi  = tid & 127;
    const int cb  = (tid >> 7) << 4;
    const int pos = TI * 128 + pi;
#pragma unroll 4
    for (int i = 0; i < 16; ++i) {
        const int co = cb + i;
        const float gi = gates[co * 128 + pi]         + lds_b[co];
        const float gf = gates[(32 + co) * 128 + pi]  + lds_b[32 + co];
        const float gc = gates[(64 + co) * 128 + pi]  + lds_b[64 + co];
        const float go = gates[(96 + co) * 128 + pi]  + lds_b[96 + co];

        const size_t ci = (size_t)(b * COUT + co) * HW + pos;
        const float c0  = (t == 0) ? 0.0f : c_state[ci];
        const float ig  = 1.0f / (1.0f + expf(-(gi + Wci[co * HW + pos] * c0)));
        const float fg  = 1.0f / (1.0f + expf(-(gf + Wcf[co * HW + pos] * c0)));
        const float cn  = fg * c0 + ig * tanhf(gc);
        const float og  = 1.0f / (1.0f + expf(-(go + Wco[co * HW + pos] * cn)));
        const float hn  = og * tanhf(cn);

        c_state[ci] = cn;
        out[((size_t)(b * COUT + co) * NT + t) * HW + pos] = hn;
    }
}

extern "C" void kernel_launch(void* const* d_in, const int* in_sizes, int n_in,
                              void* d_out, int out_size, void* d_ws, size_t ws_size,
                              hipStream_t stream) {
    const float* X    = (const float*)d_in[0];
    const float* Wf   = (const float*)d_in[1];
    const float* bias = (const float*)d_in[2];
    const float* Wci  = (const float*)d_in[3];
    const float* Wcf  = (const float*)d_in[4];
    const float* Wco  = (const float*)d_in[5];
    float* out = (float*)d_out;

    float* c_state = (float*)d_ws;                                    // 8,388,608 B
    unsigned short* Wbf = (unsigned short*)((char*)d_ws + 8388608);   // 110,592 B

    prep_w<<<216, 256, 0, stream>>>(Wf, Wbf);
    for (int t = 0; t < NT; ++t) {
        convlstm_step<<<Bn * 32, NTHREADS, 0, stream>>>(
            X, Wbf, bias, Wci, Wcf, Wco, out, c_state, t);
    }
}

// Round 3
// 637.711 us; speedup vs baseline: 9.4256x; 1.0965x over previous
//
#include <hip/hip_runtime.h>
#include <math.h>

#define Bn   16
#define CIN  8
#define NT   20
#define HH   64
#define WW   64
#define COUT 32
#define HW   4096
#define NTHREADS 256

typedef __attribute__((ext_vector_type(8)))  short bf16x8;
typedef __attribute__((ext_vector_type(16))) float f32x16;
typedef __attribute__((ext_vector_type(4)))  int   int4v;

__device__ inline unsigned short f2bf(float f) {
    unsigned u = __builtin_bit_cast(unsigned, f);
    u += 0x7fffu + ((u >> 16) & 1u);          // round-to-nearest-even
    return (unsigned short)(u >> 16);
}

__device__ inline float sigm(float x) {
    return 1.0f / (1.0f + __expf(-x));
}
__device__ inline float tanh_fast(float x) {
    x = fminf(fmaxf(x, -15.0f), 15.0f);
    float e = __expf(2.0f * x);
    return (e - 1.0f) / (e + 1.0f);
}

// Build A-fragment-ready bf16 weights in ws, with gate-interleaved M:
// fragment row m' holds original weight row (g*32 + co) where co=m'>>2, g=m'&3.
// Wbf linear index = (((tap*3 + kb)*2 + half)*128 + m')*8 + e, ch = kb*16+half*8+e
__global__ __launch_bounds__(256) void prep_w(const float* __restrict__ W,
                                              unsigned short* __restrict__ Wbf) {
    int idx = blockIdx.x * 256 + threadIdx.x;        // 9*3*2*128*8 = 55296 total
    if (idx >= 9 * 3 * 2 * 128 * 8) return;
    int e    = idx & 7;
    int m    = (idx >> 3) & 127;
    int half = (idx >> 10) & 1;
    int fk   = idx >> 11;            // tap*3 + kb
    int kb   = fk % 3;
    int tap  = fk / 3;
    int ch   = kb * 16 + half * 8 + e;
    int co   = m >> 2;
    int g    = m & 3;
    float v = 0.0f;
    if (ch < 40) v = W[(size_t)((g * 32 + co) * 40 + ch) * 9 + tap];
    Wbf[idx] = f2bf(v);
}

__global__ __launch_bounds__(NTHREADS, 2) void convlstm_step(
    const float* __restrict__ X,                 // (B, CIN, T, H, W) fp32
    const unsigned short* __restrict__ Wbf,      // prepped bf16 weights (permuted M)
    const float* __restrict__ bias,              // (128)
    const float* __restrict__ Wci,
    const float* __restrict__ Wcf,
    const float* __restrict__ Wco,
    float* __restrict__ out,                     // (B, COUT, T, H, W); h history lives here
    float* __restrict__ c_state,                 // (B, COUT, H, W) in ws
    int t)
{
    // LDS: swizzled bf16 input tile (33792 B) + bias cache (512 B). No gates buffer.
    __shared__ __align__(16) unsigned char smem[33792 + 512];
    float* lds_b = (float*)(smem + 33792);

    const int tid = threadIdx.x;
    const int b   = blockIdx.x >> 5;    // batch
    const int TI  = blockIdx.x & 31;    // tile: rows 2TI, 2TI+1 (all 64 cols)
    const int r0  = TI * 2;

    // ---- merged phase: targeted halo/pad zero + bias + interior fill ----
    // Zero only slots Pass-B never writes: lc=0 cell (8 slots/row), lc=65 cell
    // (8 slots/row), and the ch40-47 pad slot (cidx=5) of lc=1..64 (64/row).
    {
        int4v z = {0, 0, 0, 0};
        for (int zi = tid; zi < 320; zi += NTHREADS) {
            int lr = zi / 80;
            int u  = zi - lr * 80;
            int pcell, slot;
            if (u < 8)       { pcell = lr * 33;      slot = u; }          // lc=0
            else if (u < 16) { pcell = lr * 33 + 32; slot = u; }          // lc=65
            else {
                int lc = u - 15;                                          // 1..64
                pcell = lr * 33 + (lc >> 1);
                slot  = (((lc & 1) << 3) | 5) ^ ((lc >> 1) & 15);
            }
            *(int4v*)(smem + pcell * 256 + slot * 16) = z;
        }
        if (tid < 128) lds_b[tid] = bias[tid];
    }

    // interior fill: tile cell (lr 0..3, lc 1..64) x ch 0..39.
    // slot = ((lc&1)<<3 | (ch>>3)) ^ ((lc>>1)&15); byte = (lr*33+(lc>>1))*256 + slot*16 + (ch&7)*2
    for (int j = 0; j < 40; ++j) {
        int idx = tid + j * 256;        // 4 rows * 40 ch * 64 cols = 10240
        int col = idx & 63;
        int rc  = idx >> 6;             // 0..159
        int lr  = rc / 40;
        int ch  = rc - lr * 40;
        int gr  = r0 + lr - 1;
        float v = 0.0f;
        if ((unsigned)gr < 64u) {
            if (ch < 8)
                v = X[(((size_t)(b * CIN + ch) * NT + t) << 12) + (gr << 6) + col];
            else if (t > 0)
                v = out[(((size_t)(b * COUT + (ch - 8)) * NT + (t - 1)) << 12) + (gr << 6) + col];
        }
        int lc   = col + 1;
        int slot = (((lc & 1) << 3) + (ch >> 3)) ^ ((lc >> 1) & 15);
        int byte = (lr * 33 + (lc >> 1)) * 256 + slot * 16 + (ch & 7) * 2;
        *(unsigned short*)(smem + byte) = f2bf(v);
    }

    // ---- A-fragments: 27 per wave (9 taps x 3 k-blocks), from L2-resident Wbf ----
    const int wid  = tid >> 6;          // m-block (8 co's, gate-interleaved)
    const int lane = tid & 63;
    const int lm   = lane & 31;
    const int half = lane >> 5;

    bf16x8 Af[27];
#pragma unroll
    for (int f = 0; f < 27; ++f)
        Af[f] = *(const bf16x8*)(Wbf + (size_t)((f * 2 + half) * 128 + wid * 32 + lm) * 8);

    f32x16 acc[4];
#pragma unroll
    for (int nb = 0; nb < 4; ++nb)
#pragma unroll
        for (int r = 0; r < 16; ++r) acc[nb][r] = 0.0f;

    __syncthreads();

    // ---- K loop: 9 taps x 3 k-blocks x 4 n-blocks ----
    __builtin_amdgcn_s_setprio(1);
#pragma unroll
    for (int dy = 0; dy < 3; ++dy)
#pragma unroll
        for (int dx = 0; dx < 3; ++dx)
#pragma unroll
            for (int kb = 0; kb < 3; ++kb) {
                const int f    = (dy * 3 + dx) * 3 + kb;
                const int cidx = kb * 2 + half;
#pragma unroll
                for (int nb = 0; nb < 4; ++nb) {
                    const int lr   = (nb >> 1) + dy;
                    const int lc   = lm + (nb & 1) * 32 + dx;
                    const int slot = (((lc & 1) << 3) + cidx) ^ ((lc >> 1) & 15);
                    const bf16x8 bf =
                        *(const bf16x8*)(smem + (lr * 33 + (lc >> 1)) * 256 + slot * 16);
                    acc[nb] = __builtin_amdgcn_mfma_f32_32x32x16_bf16(Af[f], bf, acc[nb], 0, 0, 0);
                }
            }
    __builtin_amdgcn_s_setprio(0);

    // ---- in-register LSTM epilogue ----
    // C layout: col = lane&31 (n), row_local = (r&3) + 8*(r>>2) + 4*half.
    // Permuted M: gate = r&3, co = wid*8 + 2*(r>>2) + half. All 4 gates of a
    // (co,pos) sit in acc[nb][4j..4j+3] of one lane.
#pragma unroll
    for (int nb = 0; nb < 4; ++nb) {
        const int pos = TI * 128 + nb * 32 + lm;
#pragma unroll
        for (int j = 0; j < 4; ++j) {
            const int co = wid * 8 + 2 * j + half;
            const size_t ci  = (((size_t)(b * COUT + co)) << 12) + pos;
            const int   wofs = (co << 12) + pos;
            const float c0 = (t == 0) ? 0.0f : c_state[ci];

            const float gi = acc[nb][4 * j + 0] + lds_b[co]      + Wci[wofs] * c0;
            const float gf = acc[nb][4 * j + 1] + lds_b[32 + co] + Wcf[wofs] * c0;
            const float gc = acc[nb][4 * j + 2] + lds_b[64 + co];
            const float gq = acc[nb][4 * j + 3] + lds_b[96 + co];

            const float ig = sigm(gi);
            const float fg = sigm(gf);
            const float cn = fg * c0 + ig * tanh_fast(gc);
            const float og = sigm(gq + Wco[wofs] * cn);
            const float hn = og * tanh_fast(cn);

            c_state[ci] = cn;
            out[(((size_t)(b * COUT + co) * NT + t) << 12) + pos] = hn;
        }
    }
}

extern "C" void kernel_launch(void* const* d_in, const int* in_sizes, int n_in,
                              void* d_out, int out_size, void* d_ws, size_t ws_size,
                              hipStream_t stream) {
    const float* X    = (const float*)d_in[0];
    const float* Wf   = (const float*)d_in[1];
    const float* bias = (const float*)d_in[2];
    const float* Wci  = (const float*)d_in[3];
    const float* Wcf  = (const float*)d_in[4];
    const float* Wco  = (const float*)d_in[5];
    float* out = (float*)d_out;

    float* c_state = (float*)d_ws;                                    // 8,388,608 B
    unsigned short* Wbf = (unsigned short*)((char*)d_ws + 8388608);   // 110,592 B

    prep_w<<<216, 256, 0, stream>>>(Wf, Wbf);
    for (int t = 0; t < NT; ++t) {
        convlstm_step<<<Bn * 32, NTHREADS, 0, stream>>>(
            X, Wbf, bias, Wci, Wcf, Wco, out, c_state, t);
    }
}